// Round 1
// baseline (1161.118 us; speedup 1.0000x reference)
//
#include <hip/hip_runtime.h>
#include <hip/hip_bf16.h>

// SingleStreamBlock fused pipeline, all-bf16 MFMA datapath.
// ws layout (~334 MB): partials | mod | x | wT(shared w1t/w2t) | proj | qr | kr | vt | A2

#define DEV static __device__ __forceinline__

typedef __attribute__((ext_vector_type(4))) float f32x4;
typedef __attribute__((ext_vector_type(8))) short s8v;   // 8 x bf16 (4 VGPRs)

DEV unsigned short f2bf(float f) {
  union { float f; unsigned u; } v; v.f = f;
  unsigned r = v.u + 0x7fffu + ((v.u >> 16) & 1u);
  return (unsigned short)(r >> 16);
}
DEV float bf2f(unsigned short b) {
  union { unsigned u; float f; } v; v.u = ((unsigned)b) << 16; return v.f;
}

// ---------------- mod = silu(vec) @ mod_w + mod_b (split-K GEMV) ----------------
__global__ __launch_bounds__(256) void modvec_partial(
    const float* __restrict__ vec, const float* __restrict__ mod_w, float* __restrict__ part) {
  __shared__ float s[384];
  const int tid = threadIdx.x;
  const int i0 = blockIdx.y * 384;
  for (int i = tid; i < 384; i += 256) {
    float v = vec[i0 + i];
    s[i] = v / (1.f + __expf(-v));
  }
  __syncthreads();
  const int j = blockIdx.x * 256 + tid;
  float acc = 0.f;
#pragma unroll 8
  for (int i = 0; i < 384; ++i) acc += s[i] * mod_w[(size_t)(i0 + i) * 9216 + j];
  part[(size_t)blockIdx.y * 9216 + j] = acc;
}

__global__ __launch_bounds__(256) void modvec_reduce(
    const float* __restrict__ part, const float* __restrict__ mod_b, float* __restrict__ mod) {
  const int j = blockIdx.x * 256 + threadIdx.x;
  float a = mod_b[j];
#pragma unroll
  for (int y = 0; y < 8; ++y) a += part[(size_t)y * 9216 + j];
  mod[j] = a;
}

// ---------------- x = (1+scale)*LN(img) + shift  -> bf16 ----------------
__global__ __launch_bounds__(256) void ln_mod_kernel(
    const float* __restrict__ img, const float* __restrict__ mod, unsigned short* __restrict__ x) {
  const int l = blockIdx.x, tid = threadIdx.x;
  const int wave = tid >> 6;
  const f32x4* row = (const f32x4*)(img + (size_t)l * 3072);
  f32x4 v[3];
  float s = 0.f, s2 = 0.f;
#pragma unroll
  for (int i = 0; i < 3; ++i) {
    v[i] = row[tid + i * 256];
#pragma unroll
    for (int c = 0; c < 4; ++c) { s += v[i][c]; s2 += v[i][c] * v[i][c]; }
  }
#pragma unroll
  for (int m = 1; m < 64; m <<= 1) { s += __shfl_xor(s, m); s2 += __shfl_xor(s2, m); }
  __shared__ float rs[4], rs2[4];
  if ((tid & 63) == 0) { rs[wave] = s; rs2[wave] = s2; }
  __syncthreads();
  s = rs[0] + rs[1] + rs[2] + rs[3];
  s2 = rs2[0] + rs2[1] + rs2[2] + rs2[3];
  const float mu = s * (1.f / 3072.f);
  const float var = s2 * (1.f / 3072.f) - mu * mu;
  const float inv = rsqrtf(var + 1e-6f);
#pragma unroll
  for (int i = 0; i < 3; ++i) {
    int d0 = (tid + i * 256) * 4;
    unsigned out[2];
    unsigned short o[4];
#pragma unroll
    for (int c = 0; c < 4; ++c) {
      int d = d0 + c;
      float val = (1.f + mod[3072 + d]) * ((v[i][c] - mu) * inv) + mod[d];
      o[c] = f2bf(val);
    }
    out[0] = o[0] | ((unsigned)o[1] << 16);
    out[1] = o[2] | ((unsigned)o[3] << 16);
    *(uint2*)(x + (size_t)l * 3072 + d0) = make_uint2(out[0], out[1]);
  }
}

// ---------------- W (K,N) f32 -> Wt (N,K) bf16 ----------------
__global__ __launch_bounds__(256) void transpose_kernel(
    const float* __restrict__ W, unsigned short* __restrict__ Wt, int K, int N) {
  __shared__ float t[64][65];
  const int k0 = blockIdx.x * 64, n0 = blockIdx.y * 64;
  const int tid = threadIdx.x;
#pragma unroll
  for (int i = 0; i < 16; ++i) {
    int idx = i * 256 + tid;
    int k = idx >> 6, n = idx & 63;
    t[k][n] = W[(size_t)(k0 + k) * N + n0 + n];
  }
  __syncthreads();
#pragma unroll
  for (int i = 0; i < 8; ++i) {
    int idx = i * 256 + tid;
    int n = idx >> 5, kp = idx & 31;
    unsigned lo = f2bf(t[2 * kp][n]);
    unsigned hi = f2bf(t[2 * kp + 1][n]);
    *(unsigned*)&Wt[(size_t)(n0 + n) * K + k0 + 2 * kp] = lo | (hi << 16);
  }
}

// ---------------- 128x128 bf16 MFMA GEMM: C = A(M,K) @ Bt(N,K)^T + bias ----------------
// LDS tile: 128 rows x 32 k, pair-packed rows (2 m-rows per 128B LDS row) with XOR-8
// swizzle -> 2-way (free) bank pattern on ds_read_b128 fragment loads.
DEV int lds_off(int r, int kc) {
  int lr = r >> 1;
  int c8 = (((r & 1) << 2) | kc) ^ (lr & 7);
  return lr * 64 + c8 * 8;  // ushort elements
}

template <int EPI>
__global__ __launch_bounds__(256) void gemm_kernel(
    const unsigned short* __restrict__ A, const unsigned short* __restrict__ Bt,
    const float* __restrict__ bias, void* __restrict__ Cout,
    const float* __restrict__ img, const float* __restrict__ mod, int K, int N) {
  __shared__ unsigned short lds[2][2][4096];
  const int tid = threadIdx.x;
  const int lane = tid & 63;
  const int wm = (tid >> 7) & 1, wn = (tid >> 6) & 1;
  const int m0 = blockIdx.x * 128, n0 = blockIdx.y * 128;
  const int nK = K >> 5;

  const int r0 = tid >> 2, kc = tid & 3;
  const unsigned short* Ar0 = A + (size_t)(m0 + r0) * K + kc * 8;
  const unsigned short* Ar1 = A + (size_t)(m0 + r0 + 64) * K + kc * 8;
  const unsigned short* Br0 = Bt + (size_t)(n0 + r0) * K + kc * 8;
  const unsigned short* Br1 = Bt + (size_t)(n0 + r0 + 64) * K + kc * 8;
  const int la0 = lds_off(r0, kc), la1 = lds_off(r0 + 64, kc);

  f32x4 acc[4][4];
#pragma unroll
  for (int i = 0; i < 4; ++i)
#pragma unroll
    for (int j = 0; j < 4; ++j) acc[i][j] = (f32x4){0.f, 0.f, 0.f, 0.f};

  s8v ra0 = *(const s8v*)Ar0, ra1 = *(const s8v*)Ar1;
  s8v rb0 = *(const s8v*)Br0, rb1 = *(const s8v*)Br1;
  *(s8v*)&lds[0][0][la0] = ra0; *(s8v*)&lds[0][0][la1] = ra1;
  *(s8v*)&lds[0][1][la0] = rb0; *(s8v*)&lds[0][1][la1] = rb1;

  for (int t = 0; t < nK; ++t) {
    __syncthreads();
    const int cur = t & 1;
    const bool pre = (t + 1 < nK);
    if (pre) {
      const int ko = (t + 1) << 5;
      ra0 = *(const s8v*)(Ar0 + ko); ra1 = *(const s8v*)(Ar1 + ko);
      rb0 = *(const s8v*)(Br0 + ko); rb1 = *(const s8v*)(Br1 + ko);
    }
    s8v af[4], bf[4];
#pragma unroll
    for (int i = 0; i < 4; ++i) {
      af[i] = *(const s8v*)&lds[cur][0][lds_off(wm * 64 + i * 16 + (lane & 15), lane >> 4)];
      bf[i] = *(const s8v*)&lds[cur][1][lds_off(wn * 64 + i * 16 + (lane & 15), lane >> 4)];
    }
#pragma unroll
    for (int i = 0; i < 4; ++i)
#pragma unroll
      for (int j = 0; j < 4; ++j)
        acc[i][j] = __builtin_amdgcn_mfma_f32_16x16x32_bf16(af[i], bf[j], acc[i][j], 0, 0, 0);
    if (pre) {
      const int nb = cur ^ 1;
      *(s8v*)&lds[nb][0][la0] = ra0; *(s8v*)&lds[nb][0][la1] = ra1;
      *(s8v*)&lds[nb][1][la0] = rb0; *(s8v*)&lds[nb][1][la1] = rb1;
    }
  }

  const int mb = m0 + wm * 64, nb = n0 + wn * 64;
#pragma unroll
  for (int j = 0; j < 4; ++j) {
    const int n = nb + j * 16 + (lane & 15);
    const float bj = bias[n];
    const float gj = (EPI == 1) ? mod[6144 + n] : 0.f;
#pragma unroll
    for (int i = 0; i < 4; ++i) {
      const int mr = mb + i * 16 + ((lane >> 4) << 2);
#pragma unroll
      for (int r = 0; r < 4; ++r) {
        const float v = acc[i][j][r] + bj;
        if (EPI == 0) {
          ((unsigned short*)Cout)[(size_t)(mr + r) * N + n] = f2bf(v);
        } else {
          const size_t ix = (size_t)(mr + r) * N + n;
          ((float*)Cout)[ix] = img[ix] + gj * v;
        }
      }
    }
  }
}

// ---------------- RMSnorm(q,k) + RoPE + V-transpose ----------------
DEV void qk_one(const unsigned short* src, const float* sc, const f32x4 pe4, float extra,
                unsigned short* dst, int lane) {
  unsigned xx = *(const unsigned*)(src + 2 * lane);
  float x0 = bf2f((unsigned short)(xx & 0xffff));
  float x1 = bf2f((unsigned short)(xx >> 16));
  float ss = x0 * x0 + x1 * x1;
#pragma unroll
  for (int m = 1; m < 64; m <<= 1) ss += __shfl_xor(ss, m);
  const float inv = rsqrtf(ss * (1.f / 128.f) + 1e-6f);
  x0 *= inv * sc[2 * lane];
  x1 *= inv * sc[2 * lane + 1];
  float o0 = (pe4.x * x0 + pe4.y * x1) * extra;
  float o1 = (pe4.z * x0 + pe4.w * x1) * extra;
  *(unsigned*)(dst + 2 * lane) = (unsigned)f2bf(o0) | ((unsigned)f2bf(o1) << 16);
}

__global__ __launch_bounds__(256) void qk_prep_kernel(
    const unsigned short* __restrict__ proj, const float* __restrict__ pe,
    const float* __restrict__ q_scale, const float* __restrict__ k_scale,
    unsigned short* __restrict__ qr, unsigned short* __restrict__ kr,
    unsigned short* __restrict__ vt) {
  const int l = blockIdx.x;
  const int tid = threadIdx.x, lane = tid & 63, wave = tid >> 6;
  const unsigned short* row = proj + (size_t)l * 21504;
  const f32x4 pe4 = *(const f32x4*)(pe + ((size_t)l * 64 + lane) * 4);
  const float qsc = 0.08838834764831845f;  // Dh^-0.5 folded into q
#pragma unroll
  for (int hh = 0; hh < 6; ++hh) {
    const int h = wave + hh * 4;
    qk_one(row + h * 128, q_scale, pe4, qsc, qr + ((size_t)h * 2048 + l) * 128, lane);
    qk_one(row + 3072 + h * 128, k_scale, pe4, 1.f, kr + ((size_t)h * 2048 + l) * 128, lane);
    unsigned vv = *(const unsigned*)(row + 6144 + h * 128 + 2 * lane);
    vt[((size_t)h * 128 + 2 * lane) * 2048 + l] = (unsigned short)(vv & 0xffff);
    vt[((size_t)h * 128 + 2 * lane + 1) * 2048 + l] = (unsigned short)(vv >> 16);
  }
}

// ---------------- gelu(mlp) -> A2 cols [3072,15360) ----------------
__global__ __launch_bounds__(256) void gelu_kernel(
    const unsigned short* __restrict__ proj, unsigned short* __restrict__ A2) {
  const int idx = blockIdx.x * 256 + threadIdx.x;  // one 8-elem chunk
  const int r = idx / 1536, c = idx % 1536;
  s8v v = *(const s8v*)(proj + (size_t)r * 21504 + 9216 + (size_t)c * 8);
  s8v o;
#pragma unroll
  for (int e = 0; e < 8; ++e) {
    float x = bf2f((unsigned short)v[e]);
    float y = 0.7978845608f * (x + 0.044715f * x * x * x);
    float ex = __expf(2.f * y);
    float th = 1.f - 2.f / (ex + 1.f);
    o[e] = (short)f2bf(0.5f * x * (1.f + th));
  }
  *(s8v*)(A2 + (size_t)r * 15360 + 3072 + (size_t)c * 8) = o;
}

// ---------------- flash attention: per (qblock 64, head) ----------------
__global__ __launch_bounds__(256) void attn_kernel(
    const unsigned short* __restrict__ qr, const unsigned short* __restrict__ kr,
    const unsigned short* __restrict__ vt, unsigned short* __restrict__ A2) {
  __shared__ unsigned short Kt[16384];  // [kv 128][dh 128], XOR-8 chunk swizzle
  __shared__ unsigned short Vt[16384];  // [dh 128][kv 128], XOR-8 chunk swizzle
  __shared__ unsigned short P[4][2048]; // per-wave [q 16][kv 128], XOR-8 swizzle
  const int tid = threadIdx.x, lane = tid & 63, wave = tid >> 6;
  const int h = blockIdx.y, q0 = blockIdx.x * 64 + wave * 16;

  s8v qf[4];
  {
    const unsigned short* qb = qr + ((size_t)h * 2048 + q0 + (lane & 15)) * 128;
#pragma unroll
    for (int ks = 0; ks < 4; ++ks) qf[ks] = *(const s8v*)(qb + ks * 32 + (lane >> 4) * 8);
  }
  f32x4 o[8];
#pragma unroll
  for (int i = 0; i < 8; ++i) o[i] = (f32x4){0.f, 0.f, 0.f, 0.f};
  float m_r[4] = {-3e38f, -3e38f, -3e38f, -3e38f};
  float l_r[4] = {0.f, 0.f, 0.f, 0.f};

  for (int kb = 0; kb < 16; ++kb) {
    __syncthreads();  // all waves done reading previous K/V tiles
#pragma unroll
    for (int i = 0; i < 8; ++i) {
      const int cidx = i * 256 + tid;
      const int row = cidx >> 4, slot = cidx & 15;
      const int le = row * 128 + ((slot ^ (row & 7)) << 3);
      *(s8v*)&Kt[le] =
          *(const s8v*)(kr + (((size_t)h * 2048 + (size_t)kb * 128 + row) << 7) + slot * 8);
      *(s8v*)&Vt[le] =
          *(const s8v*)(vt + (((size_t)h * 128 + row) << 11) + (size_t)kb * 128 + slot * 8);
    }
    __syncthreads();

    f32x4 s[8];
#pragma unroll
    for (int nf = 0; nf < 8; ++nf) {
      s[nf] = (f32x4){0.f, 0.f, 0.f, 0.f};
      const int rk = nf * 16 + (lane & 15);
#pragma unroll
      for (int ks = 0; ks < 4; ++ks) {
        s8v kf = *(const s8v*)&Kt[rk * 128 + (((ks * 4 + (lane >> 4)) ^ (rk & 7)) << 3)];
        s[nf] = __builtin_amdgcn_mfma_f32_16x16x32_bf16(qf[ks], kf, s[nf], 0, 0, 0);
      }
    }
    // online softmax (rows live in 16-lane groups)
    float pmax[4], resc[4], rsum[4];
#pragma unroll
    for (int r = 0; r < 4; ++r) {
      float mx = s[0][r];
#pragma unroll
      for (int nf = 1; nf < 8; ++nf) mx = fmaxf(mx, s[nf][r]);
#pragma unroll
      for (int m = 1; m < 16; m <<= 1) mx = fmaxf(mx, __shfl_xor(mx, m));
      pmax[r] = mx;
      const float mn = fmaxf(m_r[r], mx);
      resc[r] = __expf(m_r[r] - mn);
      m_r[r] = mn;
      rsum[r] = 0.f;
    }
#pragma unroll
    for (int nf = 0; nf < 8; ++nf)
#pragma unroll
      for (int r = 0; r < 4; ++r) {
        s[nf][r] = __expf(s[nf][r] - m_r[r]);
        rsum[r] += s[nf][r];
      }
#pragma unroll
    for (int r = 0; r < 4; ++r) {
#pragma unroll
      for (int m = 1; m < 16; m <<= 1) rsum[r] += __shfl_xor(rsum[r], m);
      l_r[r] = l_r[r] * resc[r] + rsum[r];
    }
#pragma unroll
    for (int nf = 0; nf < 8; ++nf)
#pragma unroll
      for (int r = 0; r < 4; ++r) o[nf][r] *= resc[r];
    // P -> LDS (bf16), then PV
#pragma unroll
    for (int nf = 0; nf < 8; ++nf) {
      const int kv = nf * 16 + (lane & 15);
#pragma unroll
      for (int r = 0; r < 4; ++r) {
        const int q = ((lane >> 4) << 2) + r;
        P[wave][q * 128 + (((kv >> 3) ^ (q & 7)) << 3) + (kv & 7)] = f2bf(s[nf][r]);
      }
    }
#pragma unroll
    for (int ks = 0; ks < 4; ++ks) {
      const int qrw = lane & 15;
      s8v pf = *(const s8v*)&P[wave][qrw * 128 + (((ks * 4 + (lane >> 4)) ^ (qrw & 7)) << 3)];
#pragma unroll
      for (int nf = 0; nf < 8; ++nf) {
        const int rd = nf * 16 + (lane & 15);
        s8v vf = *(const s8v*)&Vt[rd * 128 + (((ks * 4 + (lane >> 4)) ^ (rd & 7)) << 3)];
        o[nf] = __builtin_amdgcn_mfma_f32_16x16x32_bf16(pf, vf, o[nf], 0, 0, 0);
      }
    }
  }
  // epilogue: normalize + store to A2 cols [0,3072)
#pragma unroll
  for (int r = 0; r < 4; ++r) m_r[r] = 1.f / l_r[r];
#pragma unroll
  for (int nf = 0; nf < 8; ++nf) {
    const int dh = nf * 16 + (lane & 15);
#pragma unroll
    for (int r = 0; r < 4; ++r) {
      const int q = q0 + ((lane >> 4) << 2) + r;
      A2[(size_t)q * 15360 + h * 128 + dh] = f2bf(o[nf][r] * m_r[r]);
    }
  }
}

// ---------------- launch ----------------
extern "C" void kernel_launch(void* const* d_in, const int* in_sizes, int n_in,
                              void* d_out, int out_size, void* d_ws, size_t ws_size,
                              hipStream_t stream) {
  (void)in_sizes; (void)n_in; (void)out_size; (void)ws_size;
  const float* img    = (const float*)d_in[0];
  const float* vec    = (const float*)d_in[1];
  const float* pe     = (const float*)d_in[2];
  const float* mod_w  = (const float*)d_in[3];
  const float* mod_b  = (const float*)d_in[4];
  const float* lin1_w = (const float*)d_in[5];
  const float* lin1_b = (const float*)d_in[6];
  const float* lin2_w = (const float*)d_in[7];
  const float* lin2_b = (const float*)d_in[8];
  const float* q_s    = (const float*)d_in[9];
  const float* k_s    = (const float*)d_in[10];
  float* out = (float*)d_out;

  char* ws = (char*)d_ws;
  size_t off = 0;
  auto alloc = [&](size_t b) { size_t p = off; off += (b + 255) & ~(size_t)255; return p; };
  float* part          = (float*)(ws + alloc((size_t)8 * 9216 * 4));
  float* mod           = (float*)(ws + alloc((size_t)9216 * 4));
  unsigned short* x    = (unsigned short*)(ws + alloc((size_t)2048 * 3072 * 2));
  unsigned short* wT   = (unsigned short*)(ws + alloc((size_t)21504 * 3072 * 2));  // w1t then w2t
  unsigned short* proj = (unsigned short*)(ws + alloc((size_t)2048 * 21504 * 2));
  unsigned short* qr   = (unsigned short*)(ws + alloc((size_t)24 * 2048 * 128 * 2));
  unsigned short* kr   = (unsigned short*)(ws + alloc((size_t)24 * 2048 * 128 * 2));
  unsigned short* vt   = (unsigned short*)(ws + alloc((size_t)24 * 128 * 2048 * 2));
  unsigned short* A2   = (unsigned short*)(ws + alloc((size_t)2048 * 15360 * 2));

  modvec_partial<<<dim3(36, 8), 256, 0, stream>>>(vec, mod_w, part);
  modvec_reduce<<<36, 256, 0, stream>>>(part, mod_b, mod);
  ln_mod_kernel<<<2048, 256, 0, stream>>>(img, mod, x);
  transpose_kernel<<<dim3(48, 336), 256, 0, stream>>>(lin1_w, wT, 3072, 21504);
  gemm_kernel<0><<<dim3(16, 168), 256, 0, stream>>>(x, wT, lin1_b, proj, nullptr, nullptr,
                                                    3072, 21504);
  qk_prep_kernel<<<2048, 256, 0, stream>>>(proj, pe, q_s, k_s, qr, kr, vt);
  gelu_kernel<<<12288, 256, 0, stream>>>(proj, A2);
  attn_kernel<<<dim3(32, 24), 256, 0, stream>>>(qr, kr, vt, A2);
  transpose_kernel<<<dim3(240, 48), 256, 0, stream>>>(lin2_w, wT, 15360, 3072);
  gemm_kernel<1><<<dim3(16, 24), 256, 0, stream>>>(A2, wT, lin2_b, out, img, mod, 15360, 3072);
}

// Round 4
// 966.873 us; speedup vs baseline: 1.2009x; 1.2009x over previous
//
#include <hip/hip_runtime.h>
#include <hip/hip_bf16.h>
#include <stdint.h>

// SingleStreamBlock fused pipeline, all-bf16 MFMA datapath.
// GEMMs: 256x256 8-phase counted-vmcnt schedule (T2+T3+T4+T5).

#define DEV static __device__ __forceinline__

typedef __attribute__((ext_vector_type(4))) float f32x4;
typedef __attribute__((ext_vector_type(8))) short s8v;   // 8 x bf16 (4 VGPRs)

DEV unsigned short f2bf(float f) {
  union { float f; unsigned u; } v; v.f = f;
  unsigned r = v.u + 0x7fffu + ((v.u >> 16) & 1u);
  return (unsigned short)(r >> 16);
}
DEV float bf2f(unsigned short b) {
  union { unsigned u; float f; } v; v.u = ((unsigned)b) << 16; return v.f;
}

DEV void gl_lds16(const unsigned short* g, unsigned short* l) {
  __builtin_amdgcn_global_load_lds(
      (const __attribute__((address_space(1))) unsigned int*)(uintptr_t)g,
      (__attribute__((address_space(3))) unsigned int*)(uint32_t)(uintptr_t)l,
      16, 0, 0);
}

// ---------------- mod = silu(vec) @ mod_w + mod_b (split-K GEMV) ----------------
__global__ __launch_bounds__(256) void modvec_partial(
    const float* __restrict__ vec, const float* __restrict__ mod_w, float* __restrict__ part) {
  __shared__ float s[384];
  const int tid = threadIdx.x;
  const int i0 = blockIdx.y * 384;
  for (int i = tid; i < 384; i += 256) {
    float v = vec[i0 + i];
    s[i] = v / (1.f + __expf(-v));
  }
  __syncthreads();
  const int j = blockIdx.x * 256 + tid;
  float acc = 0.f;
#pragma unroll 8
  for (int i = 0; i < 384; ++i) acc += s[i] * mod_w[(size_t)(i0 + i) * 9216 + j];
  part[(size_t)blockIdx.y * 9216 + j] = acc;
}

__global__ __launch_bounds__(256) void modvec_reduce(
    const float* __restrict__ part, const float* __restrict__ mod_b, float* __restrict__ mod) {
  const int j = blockIdx.x * 256 + threadIdx.x;
  float a = mod_b[j];
#pragma unroll
  for (int y = 0; y < 8; ++y) a += part[(size_t)y * 9216 + j];
  mod[j] = a;
}

// ---------------- x = (1+scale)*LN(img) + shift  -> bf16 ----------------
__global__ __launch_bounds__(256) void ln_mod_kernel(
    const float* __restrict__ img, const float* __restrict__ mod, unsigned short* __restrict__ x) {
  const int l = blockIdx.x, tid = threadIdx.x;
  const int wave = tid >> 6;
  const f32x4* row = (const f32x4*)(img + (size_t)l * 3072);
  f32x4 v[3];
  float s = 0.f, s2 = 0.f;
#pragma unroll
  for (int i = 0; i < 3; ++i) {
    v[i] = row[tid + i * 256];
#pragma unroll
    for (int c = 0; c < 4; ++c) { s += v[i][c]; s2 += v[i][c] * v[i][c]; }
  }
#pragma unroll
  for (int m = 1; m < 64; m <<= 1) { s += __shfl_xor(s, m); s2 += __shfl_xor(s2, m); }
  __shared__ float rs[4], rs2[4];
  if ((tid & 63) == 0) { rs[wave] = s; rs2[wave] = s2; }
  __syncthreads();
  s = rs[0] + rs[1] + rs[2] + rs[3];
  s2 = rs2[0] + rs2[1] + rs2[2] + rs2[3];
  const float mu = s * (1.f / 3072.f);
  const float var = s2 * (1.f / 3072.f) - mu * mu;
  const float inv = rsqrtf(var + 1e-6f);
#pragma unroll
  for (int i = 0; i < 3; ++i) {
    int d0 = (tid + i * 256) * 4;
    unsigned out[2];
    unsigned short o[4];
#pragma unroll
    for (int c = 0; c < 4; ++c) {
      int d = d0 + c;
      float val = (1.f + mod[3072 + d]) * ((v[i][c] - mu) * inv) + mod[d];
      o[c] = f2bf(val);
    }
    out[0] = o[0] | ((unsigned)o[1] << 16);
    out[1] = o[2] | ((unsigned)o[3] << 16);
    *(uint2*)(x + (size_t)l * 3072 + d0) = make_uint2(out[0], out[1]);
  }
}

// ---------------- W (K,N) f32 -> Wt (N,K) bf16 ----------------
__global__ __launch_bounds__(256) void transpose_kernel(
    const float* __restrict__ W, unsigned short* __restrict__ Wt, int K, int N) {
  __shared__ float t[64][65];
  const int k0 = blockIdx.x * 64, n0 = blockIdx.y * 64;
  const int tid = threadIdx.x;
#pragma unroll
  for (int it = 0; it < 4; ++it) {
    const int k = it * 16 + (tid >> 4), c4 = (tid & 15) * 4;
    f32x4 v = *(const f32x4*)&W[(size_t)(k0 + k) * N + n0 + c4];
    t[k][c4] = v[0]; t[k][c4 + 1] = v[1]; t[k][c4 + 2] = v[2]; t[k][c4 + 3] = v[3];
  }
  __syncthreads();
#pragma unroll
  for (int it = 0; it < 2; ++it) {
    const int idx = it * 256 + tid;
    const int n = idx >> 3, k8 = (idx & 7) * 8;
    s8v o;
#pragma unroll
    for (int e = 0; e < 8; ++e) o[e] = (short)f2bf(t[k8 + e][n]);
    *(s8v*)&Wt[(size_t)(n0 + n) * K + k0 + k8] = o;
  }
}

// ---------------- 256x256 8-phase bf16 MFMA GEMM ----------------
// C = A(M=2048,K) @ Bt(N,K)^T. EPI=0: +bias -> bf16. EPI=2: f32 partial (split-K).
// LDS ring: parity(2) x op(2:A,B) x half(2: 128 rows) x 16KiB. Swizzle: 16B-slot
// c16 ^= (row&7) applied on global source (stage) and ds_read addr.
template <int EPI>
__global__ __launch_bounds__(512, 2) void gemm256_kernel(
    const unsigned short* __restrict__ A, const unsigned short* __restrict__ Bt,
    const float* __restrict__ bias, void* __restrict__ Cout,
    int K, int N, int nTile, int nBN) {
  __shared__ unsigned short lds[65536];  // 128 KiB
  const int tid = threadIdx.x;
  const int lane = tid & 63, w = tid >> 6;
  const int wm = w >> 2, wn = w & 3;
  const int l15 = lane & 15, l4 = lane >> 4;

  int bid = blockIdx.x;
  const int nwg = gridDim.x;
  bid = (bid & 7) * (nwg >> 3) + (bid >> 3);   // XCD-aware swizzle (grid % 8 == 0)
  const int bz = bid / (nBN << 3);
  const int rem = bid - bz * (nBN << 3);
  const int m0 = (rem & 7) << 8;
  const int n0 = (rem >> 3) << 8;
  const int kOff = bz * nTile * 64;

  const int sr = (w << 3) + (lane >> 3);               // staging row within 64-chunk
  const int skc = ((lane & 7) ^ (sr & 7)) << 3;        // pre-swizzled source k-chunk
  const size_t aBase = (size_t)m0 * K + kOff;
  const size_t bBase = (size_t)n0 * K + kOff;

  const int xs0 = (l4 ^ (l15 & 7)) << 3;
  const int xs1 = ((4 + l4) ^ (l15 & 7)) << 3;
  int aRow[4], bRow[2];
#pragma unroll
  for (int i = 0; i < 4; ++i) aRow[i] = (wm * 64 + i * 16 + l15) * 64;
#pragma unroll
  for (int j = 0; j < 2; ++j) bRow[j] = (wn * 32 + j * 16 + l15) * 64;

  f32x4 acc[2][2][4][2];
#pragma unroll
  for (int mq = 0; mq < 2; ++mq)
#pragma unroll
    for (int nq = 0; nq < 2; ++nq)
#pragma unroll
      for (int i = 0; i < 4; ++i)
#pragma unroll
        for (int j = 0; j < 2; ++j) acc[mq][nq][i][j] = (f32x4){0.f, 0.f, 0.f, 0.f};

#define STAGE(op, h, par, kt)                                                        \
  do {                                                                               \
    const unsigned short* _s = (op) ? Bt : A;                                        \
    const size_t _b = (op) ? bBase : aBase;                                          \
    unsigned short* _d = &lds[((par) << 15) + ((op) << 14) + ((h) << 13) + (w << 9)];\
    gl_lds16(_s + _b + (size_t)((h) * 128 + sr) * K + (kt) * 64 + skc, _d);          \
    gl_lds16(_s + _b + (size_t)((h) * 128 + 64 + sr) * K + (kt) * 64 + skc, _d + 4096);\
  } while (0)

#define FRAGP(op, h, rowoff, xsv) \
  (*(const s8v*)&lds[pB + ((op) << 14) + ((h) << 13) + (rowoff) + (xsv)])

#define PH_MID()                                            \
  __builtin_amdgcn_s_barrier();                             \
  asm volatile("s_waitcnt lgkmcnt(0)" ::: "memory");        \
  __builtin_amdgcn_sched_barrier(0);                        \
  __builtin_amdgcn_s_setprio(1)

#define PH_END()                                            \
  __builtin_amdgcn_s_setprio(0);                            \
  asm volatile("s_waitcnt vmcnt(10)" ::: "memory");         \
  __builtin_amdgcn_s_barrier()

#define MFMA_QUAD(mq, nq)                                                              \
  _Pragma("unroll") for (int i = 0; i < 4; ++i) _Pragma("unroll") for (int j = 0; j < 2; ++j) { \
    acc[mq][nq][i][j] =                                                                \
        __builtin_amdgcn_mfma_f32_16x16x32_bf16(a[i][0], b[nq][j][0], acc[mq][nq][i][j], 0, 0, 0); \
    acc[mq][nq][i][j] =                                                                \
        __builtin_amdgcn_mfma_f32_16x16x32_bf16(a[i][1], b[nq][j][1], acc[mq][nq][i][j], 0, 0, 0); \
  }

  // prologue: A0(0),B0(0),B1(0),A1(0), A0(1),B0(1),B1(1)
  STAGE(0, 0, 0, 0); STAGE(1, 0, 0, 0); STAGE(1, 1, 0, 0); STAGE(0, 1, 0, 0);
  {
    const int k1 = (nTile > 1) ? 1 : 0;
    STAGE(0, 0, 1, k1); STAGE(1, 0, 1, k1); STAGE(1, 1, 1, k1);
  }
  asm volatile("s_waitcnt vmcnt(10)" ::: "memory");
  __builtin_amdgcn_s_barrier();

  s8v a[4][2], b[2][2][2];
#pragma unroll 2
  for (int t = 0; t < nTile; ++t) {
    const int pB = (t & 1) << 15;
    const int kt1 = (t + 1 < nTile) ? t + 1 : 0;
    const int kt2 = (t + 2 < nTile) ? t + 2 : 0;
    // ---- P0: read A-half0 + B-half0; stage A1(t+1) ----
#pragma unroll
    for (int i = 0; i < 4; ++i) { a[i][0] = FRAGP(0, 0, aRow[i], xs0); a[i][1] = FRAGP(0, 0, aRow[i], xs1); }
#pragma unroll
    for (int j = 0; j < 2; ++j) { b[0][j][0] = FRAGP(1, 0, bRow[j], xs0); b[0][j][1] = FRAGP(1, 0, bRow[j], xs1); }
    STAGE(0, 1, (t + 1) & 1, kt1);
    PH_MID();
    MFMA_QUAD(0, 0);
    PH_END();
    // ---- P1: read B-half1; stage A0(t+2) ----
#pragma unroll
    for (int j = 0; j < 2; ++j) { b[1][j][0] = FRAGP(1, 1, bRow[j], xs0); b[1][j][1] = FRAGP(1, 1, bRow[j], xs1); }
    STAGE(0, 0, t & 1, kt2);
    PH_MID();
    MFMA_QUAD(0, 1);
    PH_END();
    // ---- P2: read A-half1; stage B0(t+2) ----
#pragma unroll
    for (int i = 0; i < 4; ++i) { a[i][0] = FRAGP(0, 1, aRow[i], xs0); a[i][1] = FRAGP(0, 1, aRow[i], xs1); }
    STAGE(1, 0, t & 1, kt2);
    PH_MID();
    MFMA_QUAD(1, 0);
    PH_END();
    // ---- P3: stage B1(t+2) ----
    STAGE(1, 1, t & 1, kt2);
    PH_MID();
    MFMA_QUAD(1, 1);
    PH_END();
  }

  // Drain ALL outstanding global_load_lds before epilogue/exit: without this,
  // zombie LDS-DMA can land after the workgroup's LDS is reallocated to a new
  // workgroup -> intermittent corruption under graph replay (Round 3 failure).
  asm volatile("s_waitcnt vmcnt(0)" ::: "memory");
  __builtin_amdgcn_s_barrier();

#pragma unroll
  for (int mq = 0; mq < 2; ++mq)
#pragma unroll
    for (int nq = 0; nq < 2; ++nq)
#pragma unroll
      for (int j = 0; j < 2; ++j) {
        const int col = n0 + nq * 128 + wn * 32 + j * 16 + l15;
        const float bj = (EPI == 0) ? bias[col] : 0.f;
#pragma unroll
        for (int i = 0; i < 4; ++i) {
          const int row0 = m0 + mq * 128 + wm * 64 + i * 16 + (l4 << 2);
#pragma unroll
          for (int r = 0; r < 4; ++r) {
            if (EPI == 0)
              ((unsigned short*)Cout)[(size_t)(row0 + r) * N + col] = f2bf(acc[mq][nq][i][j][r] + bj);
            else
              ((float*)Cout)[(size_t)bz * 2048 * N + (size_t)(row0 + r) * N + col] =
                  acc[mq][nq][i][j][r];
          }
        }
      }
#undef STAGE
#undef FRAGP
#undef PH_MID
#undef PH_END
#undef MFMA_QUAD
}

// ---------------- gemm2 split-K reduce + gate + residual ----------------
__global__ __launch_bounds__(256) void reduce2_kernel(
    const float* __restrict__ part, const float* __restrict__ img,
    const float* __restrict__ mod, const float* __restrict__ bias, float* __restrict__ out) {
  const size_t idx = ((size_t)blockIdx.x * 256 + threadIdx.x) * 4;
  const int col = (int)(idx % 3072);
  f32x4 p0 = *(const f32x4*)(part + idx);
  f32x4 p1 = *(const f32x4*)(part + 6291456 + idx);
  f32x4 im = *(const f32x4*)(img + idx);
  f32x4 o;
#pragma unroll
  for (int e = 0; e < 4; ++e)
    o[e] = im[e] + mod[6144 + col + e] * (p0[e] + p1[e] + bias[col + e]);
  *(f32x4*)(out + idx) = o;
}

// ---------------- RMSnorm(q,k) + RoPE + V-transpose ----------------
DEV void qk_one(const unsigned short* src, const float* sc, const f32x4 pe4, float extra,
                unsigned short* dst, int lane) {
  unsigned xx = *(const unsigned*)(src + 2 * lane);
  float x0 = bf2f((unsigned short)(xx & 0xffff));
  float x1 = bf2f((unsigned short)(xx >> 16));
  float ss = x0 * x0 + x1 * x1;
#pragma unroll
  for (int m = 1; m < 64; m <<= 1) ss += __shfl_xor(ss, m);
  const float inv = rsqrtf(ss * (1.f / 128.f) + 1e-6f);
  x0 *= inv * sc[2 * lane];
  x1 *= inv * sc[2 * lane + 1];
  float o0 = (pe4.x * x0 + pe4.y * x1) * extra;
  float o1 = (pe4.z * x0 + pe4.w * x1) * extra;
  *(unsigned*)(dst + 2 * lane) = (unsigned)f2bf(o0) | ((unsigned)f2bf(o1) << 16);
}

__global__ __launch_bounds__(256) void qk_prep_kernel(
    const unsigned short* __restrict__ proj, const float* __restrict__ pe,
    const float* __restrict__ q_scale, const float* __restrict__ k_scale,
    unsigned short* __restrict__ qr, unsigned short* __restrict__ kr,
    unsigned short* __restrict__ vt) {
  const int l = blockIdx.x;
  const int tid = threadIdx.x, lane = tid & 63, wave = tid >> 6;
  const unsigned short* row = proj + (size_t)l * 21504;
  const f32x4 pe4 = *(const f32x4*)(pe + ((size_t)l * 64 + lane) * 4);
  const float qsc = 0.12751743761f;  // Dh^-0.5 * log2(e) folded into q
#pragma unroll
  for (int hh = 0; hh < 6; ++hh) {
    const int h = wave + hh * 4;
    qk_one(row + h * 128, q_scale, pe4, qsc, qr + ((size_t)h * 2048 + l) * 128, lane);
    qk_one(row + 3072 + h * 128, k_scale, pe4, 1.f, kr + ((size_t)h * 2048 + l) * 128, lane);
    unsigned vv = *(const unsigned*)(row + 6144 + h * 128 + 2 * lane);
    vt[((size_t)h * 128 + 2 * lane) * 2048 + l] = (unsigned short)(vv & 0xffff);
    vt[((size_t)h * 128 + 2 * lane + 1) * 2048 + l] = (unsigned short)(vv >> 16);
  }
}

// ---------------- gelu(mlp) -> A2 cols [3072,15360) ----------------
__global__ __launch_bounds__(256) void gelu_kernel(
    const unsigned short* __restrict__ proj, unsigned short* __restrict__ A2) {
  const int idx = blockIdx.x * 256 + threadIdx.x;
  const int r = idx / 1536, c = idx % 1536;
  s8v v = *(const s8v*)(proj + (size_t)r * 21504 + 9216 + (size_t)c * 8);
  s8v o;
#pragma unroll
  for (int e = 0; e < 8; ++e) {
    float x = bf2f((unsigned short)v[e]);
    float y = 0.7978845608f * (x + 0.044715f * x * x * x);
    float ex = __expf(2.f * y);
    float th = 1.f - 2.f / (ex + 1.f);
    o[e] = (short)f2bf(0.5f * x * (1.f + th));
  }
  *(s8v*)(A2 + (size_t)r * 15360 + 3072 + (size_t)c * 8) = o;
}

// ---------------- flash attention (base-2 online softmax) ----------------
__global__ __launch_bounds__(256) void attn_kernel(
    const unsigned short* __restrict__ qr, const unsigned short* __restrict__ kr,
    const unsigned short* __restrict__ vt, unsigned short* __restrict__ A2) {
  __shared__ unsigned short Kt[16384];
  __shared__ unsigned short Vt[16384];
  __shared__ unsigned short P[4][2048];
  const int tid = threadIdx.x, lane = tid & 63, wave = tid >> 6;
  const int h = blockIdx.y, q0 = blockIdx.x * 64 + wave * 16;

  s8v qf[4];
  {
    const unsigned short* qb = qr + ((size_t)h * 2048 + q0 + (lane & 15)) * 128;
#pragma unroll
    for (int ks = 0; ks < 4; ++ks) qf[ks] = *(const s8v*)(qb + ks * 32 + (lane >> 4) * 8);
  }
  f32x4 o[8];
#pragma unroll
  for (int i = 0; i < 8; ++i) o[i] = (f32x4){0.f, 0.f, 0.f, 0.f};
  float m_r[4] = {-3e38f, -3e38f, -3e38f, -3e38f};
  float l_r[4] = {0.f, 0.f, 0.f, 0.f};

  for (int kb = 0; kb < 16; ++kb) {
    __syncthreads();
#pragma unroll
    for (int i = 0; i < 8; ++i) {
      const int cidx = i * 256 + tid;
      const int row = cidx >> 4, slot = cidx & 15;
      const int le = row * 128 + ((slot ^ (row & 7)) << 3);
      *(s8v*)&Kt[le] =
          *(const s8v*)(kr + (((size_t)h * 2048 + (size_t)kb * 128 + row) << 7) + slot * 8);
      *(s8v*)&Vt[le] =
          *(const s8v*)(vt + (((size_t)h * 128 + row) << 11) + (size_t)kb * 128 + slot * 8);
    }
    __syncthreads();

    f32x4 s[8];
#pragma unroll
    for (int nf = 0; nf < 8; ++nf) {
      s[nf] = (f32x4){0.f, 0.f, 0.f, 0.f};
      const int rk = nf * 16 + (lane & 15);
#pragma unroll
      for (int ks = 0; ks < 4; ++ks) {
        s8v kf = *(const s8v*)&Kt[rk * 128 + (((ks * 4 + (lane >> 4)) ^ (rk & 7)) << 3)];
        s[nf] = __builtin_amdgcn_mfma_f32_16x16x32_bf16(qf[ks], kf, s[nf], 0, 0, 0);
      }
    }
    float pmax[4], resc[4], rsum[4];
#pragma unroll
    for (int r = 0; r < 4; ++r) {
      float mx = s[0][r];
#pragma unroll
      for (int nf = 1; nf < 8; ++nf) mx = fmaxf(mx, s[nf][r]);
#pragma unroll
      for (int m = 1; m < 16; m <<= 1) mx = fmaxf(mx, __shfl_xor(mx, m));
      pmax[r] = mx;
      const float mn = fmaxf(m_r[r], mx);
      resc[r] = exp2f(m_r[r] - mn);
      m_r[r] = mn;
      rsum[r] = 0.f;
    }
#pragma unroll
    for (int nf = 0; nf < 8; ++nf)
#pragma unroll
      for (int r = 0; r < 4; ++r) {
        s[nf][r] = exp2f(s[nf][r] - m_r[r]);
        rsum[r] += s[nf][r];
      }
#pragma unroll
    for (int r = 0; r < 4; ++r) {
#pragma unroll
      for (int m = 1; m < 16; m <<= 1) rsum[r] += __shfl_xor(rsum[r], m);
      l_r[r] = l_r[r] * resc[r] + rsum[r];
    }
#pragma unroll
    for (int nf = 0; nf < 8; ++nf)
#pragma unroll
      for (int r = 0; r < 4; ++r) o[nf][r] *= resc[r];
#pragma unroll
    for (int nf = 0; nf < 8; ++nf) {
      const int kv = nf * 16 + (lane & 15);
#pragma unroll
      for (int r = 0; r < 4; ++r) {
        const int q = ((lane >> 4) << 2) + r;
        P[wave][q * 128 + (((kv >> 3) ^ (q & 7)) << 3) + (kv & 7)] = f2bf(s[nf][r]);
      }
    }
#pragma unroll
    for (int ks = 0; ks < 4; ++ks) {
      const int qrw = lane & 15;
      s8v pf = *(const s8v*)&P[wave][qrw * 128 + (((ks * 4 + (lane >> 4)) ^ (qrw & 7)) << 3)];
#pragma unroll
      for (int nf = 0; nf < 8; ++nf) {
        const int rd = nf * 16 + (lane & 15);
        s8v vf = *(const s8v*)&Vt[rd * 128 + (((ks * 4 + (lane >> 4)) ^ (rd & 7)) << 3)];
        o[nf] = __builtin_amdgcn_mfma_f32_16x16x32_bf16(pf, vf, o[nf], 0, 0, 0);
      }
    }
  }
#pragma unroll
  for (int r = 0; r < 4; ++r) m_r[r] = 1.f / l_r[r];
#pragma unroll
  for (int nf = 0; nf < 8; ++nf) {
    const int dh = nf * 16 + (lane & 15);
#pragma unroll
    for (int r = 0; r < 4; ++r) {
      const int q = q0 + ((lane >> 4) << 2) + r;
      A2[(size_t)q * 15360 + h * 128 + dh] = f2bf(o[nf][r] * m_r[r]);
    }
  }
}

// ---------------- launch ----------------
extern "C" void kernel_launch(void* const* d_in, const int* in_sizes, int n_in,
                              void* d_out, int out_size, void* d_ws, size_t ws_size,
                              hipStream_t stream) {
  (void)in_sizes; (void)n_in; (void)out_size; (void)ws_size;
  const float* img    = (const float*)d_in[0];
  const float* vec    = (const float*)d_in[1];
  const float* pe     = (const float*)d_in[2];
  const float* mod_w  = (const float*)d_in[3];
  const float* mod_b  = (const float*)d_in[4];
  const float* lin1_w = (const float*)d_in[5];
  const float* lin1_b = (const float*)d_in[6];
  const float* lin2_w = (const float*)d_in[7];
  const float* lin2_b = (const float*)d_in[8];
  const float* q_s    = (const float*)d_in[9];
  const float* k_s    = (const float*)d_in[10];
  float* out = (float*)d_out;

  char* ws = (char*)d_ws;
  size_t off = 0;
  auto alloc = [&](size_t b) { size_t p = off; off += (b + 255) & ~(size_t)255; return p; };
  float* part          = (float*)(ws + alloc((size_t)8 * 9216 * 4));
  float* mod           = (float*)(ws + alloc((size_t)9216 * 4));
  unsigned short* x    = (unsigned short*)(ws + alloc((size_t)2048 * 3072 * 2));
  unsigned short* wT   = (unsigned short*)(ws + alloc((size_t)21504 * 3072 * 2));  // w1t then w2t
  unsigned short* proj = (unsigned short*)(ws + alloc((size_t)2048 * 21504 * 2));
  unsigned short* qr   = (unsigned short*)(ws + alloc((size_t)24 * 2048 * 128 * 2));
  unsigned short* kr   = (unsigned short*)(ws + alloc((size_t)24 * 2048 * 128 * 2));
  unsigned short* vt   = (unsigned short*)(ws + alloc((size_t)24 * 128 * 2048 * 2));
  unsigned short* A2   = (unsigned short*)(ws + alloc((size_t)2048 * 15360 * 2));
  float* p2buf = (float*)proj;  // gemm2 split-K partials reuse dead proj buffer

  modvec_partial<<<dim3(36, 8), 256, 0, stream>>>(vec, mod_w, part);
  modvec_reduce<<<36, 256, 0, stream>>>(part, mod_b, mod);
  ln_mod_kernel<<<2048, 256, 0, stream>>>(img, mod, x);
  transpose_kernel<<<dim3(48, 336), 256, 0, stream>>>(lin1_w, wT, 3072, 21504);
  gemm256_kernel<0><<<672, 512, 0, stream>>>(x, wT, lin1_b, proj, 3072, 21504, 48, 84);
  qk_prep_kernel<<<2048, 256, 0, stream>>>(proj, pe, q_s, k_s, qr, kr, vt);
  gelu_kernel<<<12288, 256, 0, stream>>>(proj, A2);
  attn_kernel<<<dim3(32, 24), 256, 0, stream>>>(qr, kr, vt, A2);
  transpose_kernel<<<dim3(240, 48), 256, 0, stream>>>(lin2_w, wT, 15360, 3072);
  gemm256_kernel<2><<<192, 512, 0, stream>>>(A2, wT, nullptr, p2buf, 15360, 3072, 120, 12);
  reduce2_kernel<<<6144, 256, 0, stream>>>(p2buf, img, mod, lin2_b, out);
}

// Round 5
// 892.561 us; speedup vs baseline: 1.3009x; 1.0833x over previous
//
#include <hip/hip_runtime.h>
#include <hip/hip_bf16.h>
#include <stdint.h>

// SingleStreamBlock fused pipeline, all-bf16 MFMA datapath.
// GEMMs: 256x256 8-phase counted-vmcnt schedule (T2+T3+T4+T5).
// Attention: 32x32 swapped-operand flash (S^T=mfma(K,Q), O^T=mfma(V^T,P^T)),
// P in registers, K/V via global_load_lds with XOR-slot swizzle.

#define DEV static __device__ __forceinline__

typedef __attribute__((ext_vector_type(4))) float f32x4;
typedef __attribute__((ext_vector_type(16))) float f32x16;
typedef __attribute__((ext_vector_type(8))) short s8v;   // 8 x bf16 (4 VGPRs)

DEV unsigned short f2bf(float f) {
  union { float f; unsigned u; } v; v.f = f;
  unsigned r = v.u + 0x7fffu + ((v.u >> 16) & 1u);
  return (unsigned short)(r >> 16);
}
DEV float bf2f(unsigned short b) {
  union { unsigned u; float f; } v; v.u = ((unsigned)b) << 16; return v.f;
}
DEV unsigned pk2bf(float a, float b) {
  union { __hip_bfloat162 h; unsigned u; } v;
  v.h = __float22bfloat162_rn(make_float2(a, b));
  return v.u;
}

DEV void gl_lds16(const void* g, void* l) {
  __builtin_amdgcn_global_load_lds(
      (const __attribute__((address_space(1))) unsigned int*)(uintptr_t)g,
      (__attribute__((address_space(3))) unsigned int*)(uint32_t)(uintptr_t)l,
      16, 0, 0);
}

// ---------------- mod = silu(vec) @ mod_w + mod_b (split-K GEMV) ----------------
__global__ __launch_bounds__(256) void modvec_partial(
    const float* __restrict__ vec, const float* __restrict__ mod_w, float* __restrict__ part) {
  __shared__ float s[384];
  const int tid = threadIdx.x;
  const int i0 = blockIdx.y * 384;
  for (int i = tid; i < 384; i += 256) {
    float v = vec[i0 + i];
    s[i] = v / (1.f + __expf(-v));
  }
  __syncthreads();
  const int j = blockIdx.x * 256 + tid;
  float acc = 0.f;
#pragma unroll 8
  for (int i = 0; i < 384; ++i) acc += s[i] * mod_w[(size_t)(i0 + i) * 9216 + j];
  part[(size_t)blockIdx.y * 9216 + j] = acc;
}

__global__ __launch_bounds__(256) void modvec_reduce(
    const float* __restrict__ part, const float* __restrict__ mod_b, float* __restrict__ mod) {
  const int j = blockIdx.x * 256 + threadIdx.x;
  float a = mod_b[j];
#pragma unroll
  for (int y = 0; y < 8; ++y) a += part[(size_t)y * 9216 + j];
  mod[j] = a;
}

// ---------------- x = (1+scale)*LN(img) + shift  -> bf16 ----------------
__global__ __launch_bounds__(256) void ln_mod_kernel(
    const float* __restrict__ img, const float* __restrict__ mod, unsigned short* __restrict__ x) {
  const int l = blockIdx.x, tid = threadIdx.x;
  const int wave = tid >> 6;
  const f32x4* row = (const f32x4*)(img + (size_t)l * 3072);
  f32x4 v[3];
  float s = 0.f, s2 = 0.f;
#pragma unroll
  for (int i = 0; i < 3; ++i) {
    v[i] = row[tid + i * 256];
#pragma unroll
    for (int c = 0; c < 4; ++c) { s += v[i][c]; s2 += v[i][c] * v[i][c]; }
  }
#pragma unroll
  for (int m = 1; m < 64; m <<= 1) { s += __shfl_xor(s, m); s2 += __shfl_xor(s2, m); }
  __shared__ float rs[4], rs2[4];
  if ((tid & 63) == 0) { rs[wave] = s; rs2[wave] = s2; }
  __syncthreads();
  s = rs[0] + rs[1] + rs[2] + rs[3];
  s2 = rs2[0] + rs2[1] + rs2[2] + rs2[3];
  const float mu = s * (1.f / 3072.f);
  const float var = s2 * (1.f / 3072.f) - mu * mu;
  const float inv = rsqrtf(var + 1e-6f);
#pragma unroll
  for (int i = 0; i < 3; ++i) {
    int d0 = (tid + i * 256) * 4;
    unsigned out[2];
    unsigned short o[4];
#pragma unroll
    for (int c = 0; c < 4; ++c) {
      int d = d0 + c;
      float val = (1.f + mod[3072 + d]) * ((v[i][c] - mu) * inv) + mod[d];
      o[c] = f2bf(val);
    }
    out[0] = o[0] | ((unsigned)o[1] << 16);
    out[1] = o[2] | ((unsigned)o[3] << 16);
    *(uint2*)(x + (size_t)l * 3072 + d0) = make_uint2(out[0], out[1]);
  }
}

// ---------------- W (K,N) f32 -> Wt (N,K) bf16 ----------------
__global__ __launch_bounds__(256) void transpose_kernel(
    const float* __restrict__ W, unsigned short* __restrict__ Wt, int K, int N) {
  __shared__ float t[64][65];
  const int k0 = blockIdx.x * 64, n0 = blockIdx.y * 64;
  const int tid = threadIdx.x;
#pragma unroll
  for (int it = 0; it < 4; ++it) {
    const int k = it * 16 + (tid >> 4), c4 = (tid & 15) * 4;
    f32x4 v = *(const f32x4*)&W[(size_t)(k0 + k) * N + n0 + c4];
    t[k][c4] = v[0]; t[k][c4 + 1] = v[1]; t[k][c4 + 2] = v[2]; t[k][c4 + 3] = v[3];
  }
  __syncthreads();
#pragma unroll
  for (int it = 0; it < 2; ++it) {
    const int idx = it * 256 + tid;
    const int n = idx >> 3, k8 = (idx & 7) * 8;
    s8v o;
#pragma unroll
    for (int e = 0; e < 8; ++e) o[e] = (short)f2bf(t[k8 + e][n]);
    *(s8v*)&Wt[(size_t)(n0 + n) * K + k0 + k8] = o;
  }
}

// ---------------- 256x256 8-phase bf16 MFMA GEMM ----------------
template <int EPI>
__global__ __launch_bounds__(512, 2) void gemm256_kernel(
    const unsigned short* __restrict__ A, const unsigned short* __restrict__ Bt,
    const float* __restrict__ bias, void* __restrict__ Cout,
    int K, int N, int nTile, int nBN) {
  __shared__ unsigned short lds[65536];  // 128 KiB
  const int tid = threadIdx.x;
  const int lane = tid & 63, w = tid >> 6;
  const int wm = w >> 2, wn = w & 3;
  const int l15 = lane & 15, l4 = lane >> 4;

  int bid = blockIdx.x;
  const int nwg = gridDim.x;
  bid = (bid & 7) * (nwg >> 3) + (bid >> 3);   // XCD-aware swizzle (grid % 8 == 0)
  const int bz = bid / (nBN << 3);
  const int rem = bid - bz * (nBN << 3);
  const int m0 = (rem & 7) << 8;
  const int n0 = (rem >> 3) << 8;
  const int kOff = bz * nTile * 64;

  const int sr = (w << 3) + (lane >> 3);
  const int skc = ((lane & 7) ^ (sr & 7)) << 3;
  const size_t aBase = (size_t)m0 * K + kOff;
  const size_t bBase = (size_t)n0 * K + kOff;

  const int xs0 = (l4 ^ (l15 & 7)) << 3;
  const int xs1 = ((4 + l4) ^ (l15 & 7)) << 3;
  int aRow[4], bRow[2];
#pragma unroll
  for (int i = 0; i < 4; ++i) aRow[i] = (wm * 64 + i * 16 + l15) * 64;
#pragma unroll
  for (int j = 0; j < 2; ++j) bRow[j] = (wn * 32 + j * 16 + l15) * 64;

  f32x4 acc[2][2][4][2];
#pragma unroll
  for (int mq = 0; mq < 2; ++mq)
#pragma unroll
    for (int nq = 0; nq < 2; ++nq)
#pragma unroll
      for (int i = 0; i < 4; ++i)
#pragma unroll
        for (int j = 0; j < 2; ++j) acc[mq][nq][i][j] = (f32x4){0.f, 0.f, 0.f, 0.f};

#define STAGE(op, h, par, kt)                                                        \
  do {                                                                               \
    const unsigned short* _s = (op) ? Bt : A;                                        \
    const size_t _b = (op) ? bBase : aBase;                                          \
    unsigned short* _d = &lds[((par) << 15) + ((op) << 14) + ((h) << 13) + (w << 9)];\
    gl_lds16(_s + _b + (size_t)((h) * 128 + sr) * K + (kt) * 64 + skc, _d);          \
    gl_lds16(_s + _b + (size_t)((h) * 128 + 64 + sr) * K + (kt) * 64 + skc, _d + 4096);\
  } while (0)

#define FRAGP(op, h, rowoff, xsv) \
  (*(const s8v*)&lds[pB + ((op) << 14) + ((h) << 13) + (rowoff) + (xsv)])

#define PH_MID()                                            \
  __builtin_amdgcn_s_barrier();                             \
  asm volatile("s_waitcnt lgkmcnt(0)" ::: "memory");        \
  __builtin_amdgcn_sched_barrier(0);                        \
  __builtin_amdgcn_s_setprio(1)

#define PH_END()                                            \
  __builtin_amdgcn_s_setprio(0);                            \
  asm volatile("s_waitcnt vmcnt(10)" ::: "memory");         \
  __builtin_amdgcn_s_barrier()

#define MFMA_QUAD(mq, nq)                                                              \
  _Pragma("unroll") for (int i = 0; i < 4; ++i) _Pragma("unroll") for (int j = 0; j < 2; ++j) { \
    acc[mq][nq][i][j] =                                                                \
        __builtin_amdgcn_mfma_f32_16x16x32_bf16(a[i][0], b[nq][j][0], acc[mq][nq][i][j], 0, 0, 0); \
    acc[mq][nq][i][j] =                                                                \
        __builtin_amdgcn_mfma_f32_16x16x32_bf16(a[i][1], b[nq][j][1], acc[mq][nq][i][j], 0, 0, 0); \
  }

  STAGE(0, 0, 0, 0); STAGE(1, 0, 0, 0); STAGE(1, 1, 0, 0); STAGE(0, 1, 0, 0);
  {
    const int k1 = (nTile > 1) ? 1 : 0;
    STAGE(0, 0, 1, k1); STAGE(1, 0, 1, k1); STAGE(1, 1, 1, k1);
  }
  asm volatile("s_waitcnt vmcnt(10)" ::: "memory");
  __builtin_amdgcn_s_barrier();

  s8v a[4][2], b[2][2][2];
#pragma unroll 2
  for (int t = 0; t < nTile; ++t) {
    const int pB = (t & 1) << 15;
    const int kt1 = (t + 1 < nTile) ? t + 1 : 0;
    const int kt2 = (t + 2 < nTile) ? t + 2 : 0;
#pragma unroll
    for (int i = 0; i < 4; ++i) { a[i][0] = FRAGP(0, 0, aRow[i], xs0); a[i][1] = FRAGP(0, 0, aRow[i], xs1); }
#pragma unroll
    for (int j = 0; j < 2; ++j) { b[0][j][0] = FRAGP(1, 0, bRow[j], xs0); b[0][j][1] = FRAGP(1, 0, bRow[j], xs1); }
    STAGE(0, 1, (t + 1) & 1, kt1);
    PH_MID();
    MFMA_QUAD(0, 0);
    PH_END();
#pragma unroll
    for (int j = 0; j < 2; ++j) { b[1][j][0] = FRAGP(1, 1, bRow[j], xs0); b[1][j][1] = FRAGP(1, 1, bRow[j], xs1); }
    STAGE(0, 0, t & 1, kt2);
    PH_MID();
    MFMA_QUAD(0, 1);
    PH_END();
#pragma unroll
    for (int i = 0; i < 4; ++i) { a[i][0] = FRAGP(0, 1, aRow[i], xs0); a[i][1] = FRAGP(0, 1, aRow[i], xs1); }
    STAGE(1, 0, t & 1, kt2);
    PH_MID();
    MFMA_QUAD(1, 0);
    PH_END();
    STAGE(1, 1, t & 1, kt2);
    PH_MID();
    MFMA_QUAD(1, 1);
    PH_END();
  }

  // Drain outstanding global_load_lds before epilogue/exit (Round 3 lesson).
  asm volatile("s_waitcnt vmcnt(0)" ::: "memory");
  __builtin_amdgcn_s_barrier();

#pragma unroll
  for (int mq = 0; mq < 2; ++mq)
#pragma unroll
    for (int nq = 0; nq < 2; ++nq)
#pragma unroll
      for (int j = 0; j < 2; ++j) {
        const int col = n0 + nq * 128 + wn * 32 + j * 16 + l15;
        const float bj = (EPI == 0) ? bias[col] : 0.f;
#pragma unroll
        for (int i = 0; i < 4; ++i) {
          const int row0 = m0 + mq * 128 + wm * 64 + i * 16 + (l4 << 2);
#pragma unroll
          for (int r = 0; r < 4; ++r) {
            if (EPI == 0)
              ((unsigned short*)Cout)[(size_t)(row0 + r) * N + col] = f2bf(acc[mq][nq][i][j][r] + bj);
            else
              ((float*)Cout)[(size_t)bz * 2048 * N + (size_t)(row0 + r) * N + col] =
                  acc[mq][nq][i][j][r];
          }
        }
      }
#undef STAGE
#undef FRAGP
#undef PH_MID
#undef PH_END
#undef MFMA_QUAD
}

// ---------------- gemm2 split-K reduce + gate + residual ----------------
__global__ __launch_bounds__(256) void reduce2_kernel(
    const float* __restrict__ part, const float* __restrict__ img,
    const float* __restrict__ mod, const float* __restrict__ bias, float* __restrict__ out) {
  const size_t idx = ((size_t)blockIdx.x * 256 + threadIdx.x) * 4;
  const int col = (int)(idx % 3072);
  f32x4 p0 = *(const f32x4*)(part + idx);
  f32x4 p1 = *(const f32x4*)(part + 6291456 + idx);
  f32x4 im = *(const f32x4*)(img + idx);
  f32x4 o;
#pragma unroll
  for (int e = 0; e < 4; ++e)
    o[e] = im[e] + mod[6144 + col + e] * (p0[e] + p1[e] + bias[col + e]);
  *(f32x4*)(out + idx) = o;
}

// ---------------- RMSnorm(q,k) + RoPE + V-transpose ----------------
DEV void qk_one(const unsigned short* src, const float* sc, const f32x4 pe4, float extra,
                unsigned short* dst, int lane) {
  unsigned xx = *(const unsigned*)(src + 2 * lane);
  float x0 = bf2f((unsigned short)(xx & 0xffff));
  float x1 = bf2f((unsigned short)(xx >> 16));
  float ss = x0 * x0 + x1 * x1;
#pragma unroll
  for (int m = 1; m < 64; m <<= 1) ss += __shfl_xor(ss, m);
  const float inv = rsqrtf(ss * (1.f / 128.f) + 1e-6f);
  x0 *= inv * sc[2 * lane];
  x1 *= inv * sc[2 * lane + 1];
  float o0 = (pe4.x * x0 + pe4.y * x1) * extra;
  float o1 = (pe4.z * x0 + pe4.w * x1) * extra;
  *(unsigned*)(dst + 2 * lane) = (unsigned)f2bf(o0) | ((unsigned)f2bf(o1) << 16);
}

__global__ __launch_bounds__(256) void qk_prep_kernel(
    const unsigned short* __restrict__ proj, const float* __restrict__ pe,
    const float* __restrict__ q_scale, const float* __restrict__ k_scale,
    unsigned short* __restrict__ qr, unsigned short* __restrict__ kr,
    unsigned short* __restrict__ vt) {
  const int l = blockIdx.x;
  const int tid = threadIdx.x, lane = tid & 63, wave = tid >> 6;
  const unsigned short* row = proj + (size_t)l * 21504;
  const f32x4 pe4 = *(const f32x4*)(pe + ((size_t)l * 64 + lane) * 4);
  const float qsc = 0.12751743761f;  // Dh^-0.5 * log2(e) folded into q
#pragma unroll
  for (int hh = 0; hh < 6; ++hh) {
    const int h = wave + hh * 4;
    qk_one(row + h * 128, q_scale, pe4, qsc, qr + ((size_t)h * 2048 + l) * 128, lane);
    qk_one(row + 3072 + h * 128, k_scale, pe4, 1.f, kr + ((size_t)h * 2048 + l) * 128, lane);
    unsigned vv = *(const unsigned*)(row + 6144 + h * 128 + 2 * lane);
    vt[((size_t)h * 128 + 2 * lane) * 2048 + l] = (unsigned short)(vv & 0xffff);
    vt[((size_t)h * 128 + 2 * lane + 1) * 2048 + l] = (unsigned short)(vv >> 16);
  }
}

// ---------------- gelu(mlp) -> A2 cols [3072,15360) ----------------
__global__ __launch_bounds__(256) void gelu_kernel(
    const unsigned short* __restrict__ proj, unsigned short* __restrict__ A2) {
  const int idx = blockIdx.x * 256 + threadIdx.x;
  const int r = idx / 1536, c = idx % 1536;
  s8v v = *(const s8v*)(proj + (size_t)r * 21504 + 9216 + (size_t)c * 8);
  s8v o;
#pragma unroll
  for (int e = 0; e < 8; ++e) {
    float x = bf2f((unsigned short)v[e]);
    float y = 0.7978845608f * (x + 0.044715f * x * x * x);
    float ex = __expf(2.f * y);
    float th = 1.f - 2.f / (ex + 1.f);
    o[e] = (short)f2bf(0.5f * x * (1.f + th));
  }
  *(s8v*)(A2 + (size_t)r * 15360 + 3072 + (size_t)c * 8) = o;
}

// ---------------- flash attention: 32x32 swapped-operand, P in registers ----
// 4 waves x 32 q-rows = 128 q/block; KVBLK=64; grid (16, 24).
// LDS: 2 buffers x (K 16KB + V^T 16KB) = 64KB. 16B-slot XOR swizzle, source-side
// pre-swizzled for global_load_lds (rule #21). Epilogue: O^T -> LDS (264B-pitch
// rows) -> coalesced 16B global stores.
__global__ __launch_bounds__(256) void attn_kernel(
    const unsigned short* __restrict__ qr, const unsigned short* __restrict__ kr,
    const unsigned short* __restrict__ vt, unsigned short* __restrict__ A2) {
  __shared__ char lds[65536];
  const int tid = threadIdx.x, lane = tid & 63, w = tid >> 6;
  const int l31 = lane & 31, hi = lane >> 5;
  const int h = blockIdx.y;
  const int q0 = blockIdx.x * 128 + w * 32;
  const int q = q0 + l31;

  // Q fragments: B[col=q][k=d], lane holds d = ks*16 + hi*8 .. +8
  s8v qf[8];
  {
    const unsigned short* qb = qr + ((size_t)h * 2048 + q) * 128 + hi * 8;
#pragma unroll
    for (int ks = 0; ks < 8; ++ks) qf[ks] = *(const s8v*)(qb + ks * 16);
  }

  // Per-lane staging source offsets (elements), invariant over t.
  int koff[4], voff[4];
#pragma unroll
  for (int c = 0; c < 4; ++c) {
    const int ob = (w * 4 + c) * 1024 + lane * 16;   // byte offset in 16KB tile
    const int row = ob >> 8;
    const int sl = (ob >> 4) & 15;
    const int ssl = sl ^ (row & 15);
    koff[c] = row * 128 + ssl * 8;
    const int dh = row * 2 + (ssl >> 3);
    voff[c] = dh * 2048 + (ssl & 7) * 8;
  }
  const unsigned short* krH = kr + (size_t)h * 2048 * 128;
  const unsigned short* vtH = vt + (size_t)h * 128 * 2048;

  f32x16 oacc[4];
#pragma unroll
  for (int rf = 0; rf < 4; ++rf)
#pragma unroll
    for (int e = 0; e < 16; ++e) oacc[rf][e] = 0.f;
  float m = -3e38f, l = 0.f;

#define ATT_STAGE(t)                                                        \
  do {                                                                      \
    char* kb_ = lds + ((t) & 1) * 32768;                                    \
    char* vb_ = kb_ + 16384;                                                \
    _Pragma("unroll") for (int c = 0; c < 4; ++c) {                         \
      gl_lds16(krH + (size_t)(t) * 8192 + koff[c], kb_ + (w * 4 + c) * 1024); \
      gl_lds16(vtH + (size_t)(t) * 64 + voff[c], vb_ + (w * 4 + c) * 1024);   \
    }                                                                       \
  } while (0)

  ATT_STAGE(0);
  __syncthreads();

  for (int t = 0; t < 32; ++t) {
    if (t + 1 < 32) ATT_STAGE(t + 1);
    char* kb = lds + (t & 1) * 32768;
    char* vb = kb + 16384;

    // ---- S^T = K (A, rows=kv) x Q (B, cols=q) over d=128 ----
    f32x16 st[2];
#pragma unroll
    for (int rf = 0; rf < 2; ++rf)
#pragma unroll
      for (int e = 0; e < 16; ++e) st[rf][e] = 0.f;
#pragma unroll
    for (int ks = 0; ks < 8; ++ks)
#pragma unroll
      for (int rf = 0; rf < 2; ++rf) {
        const int kvr = rf * 32 + l31;
        s8v kf = *(const s8v*)(kb + kvr * 256 + (((ks * 2 + hi) ^ (kvr & 15)) << 4));
        st[rf] = __builtin_amdgcn_mfma_f32_32x32x16_bf16(kf, qf[ks], st[rf], 0, 0, 0);
      }

    // ---- online softmax: lane-local (its q = l31) + one shfl over hi ----
    float pm = st[0][0];
#pragma unroll
    for (int rf = 0; rf < 2; ++rf)
#pragma unroll
      for (int e = 0; e < 16; ++e) pm = fmaxf(pm, st[rf][e]);
    pm = fmaxf(pm, __shfl_xor(pm, 32));
    if (__any(pm - m > 11.5f)) {   // defer-max (T13, log2 units)
      const float mn = fmaxf(m, pm);
      const float rs = exp2f(m - mn);
      l *= rs;
#pragma unroll
      for (int rf = 0; rf < 4; ++rf)
#pragma unroll
        for (int e = 0; e < 16; ++e) oacc[rf][e] *= rs;
      m = mn;
    }
    // p = exp2(s - m), pack to bf16 pairs (kv 4-groups per (rb,g))
    unsigned P2[16];
#pragma unroll
    for (int rb = 0; rb < 2; ++rb)
#pragma unroll
      for (int g = 0; g < 4; ++g) {
        const float e0 = exp2f(st[rb][4 * g + 0] - m);
        const float e1 = exp2f(st[rb][4 * g + 1] - m);
        const float e2 = exp2f(st[rb][4 * g + 2] - m);
        const float e3 = exp2f(st[rb][4 * g + 3] - m);
        l += (e0 + e1) + (e2 + e3);
        P2[rb * 8 + g * 2 + 0] = pk2bf(e0, e1);
        P2[rb * 8 + g * 2 + 1] = pk2bf(e2, e3);
      }

    // ---- O^T += V^T (A, rows=dh) x P^T (B, cols=q) over kv=64 ----
#pragma unroll
    for (int ks = 0; ks < 4; ++ks) {
      const int iA = ((2 * ks) >> 2) * 8 + ((2 * ks) & 3) * 2;        // d = 2ks
      const int iB = ((2 * ks + 1) >> 2) * 8 + ((2 * ks + 1) & 3) * 2; // d = 2ks+1
      const unsigned s0 = hi ? P2[iA] : P2[iB];
      const unsigned s1 = hi ? P2[iA + 1] : P2[iB + 1];
      const unsigned r0 = (unsigned)__shfl_xor((int)s0, 32);
      const unsigned r1 = (unsigned)__shfl_xor((int)s1, 32);
      const unsigned o0 = hi ? P2[iB] : P2[iA];
      const unsigned o1 = hi ? P2[iB + 1] : P2[iA + 1];
      union { unsigned u[4]; s8v v; } pf;
      pf.u[0] = hi ? r0 : o0;
      pf.u[1] = hi ? r1 : o1;
      pf.u[2] = hi ? o0 : r0;
      pf.u[3] = hi ? o1 : r1;
#pragma unroll
      for (int rf = 0; rf < 4; ++rf) {
        const int dh = rf * 32 + l31, r = dh >> 1;
        const int sl = ((dh & 1) << 3) + ks * 2 + hi;
        s8v vf = *(const s8v*)(vb + r * 256 + ((sl ^ (r & 15)) << 4));
        oacc[rf] = __builtin_amdgcn_mfma_f32_32x32x16_bf16(vf, pf.v, oacc[rf], 0, 0, 0);
      }
    }
    __syncthreads();  // waits vmcnt(0)+lgkmcnt(0): next buffer staged, reads done
  }

  // ---- epilogue: normalize (lane-local), transpose via LDS, coalesced store ----
  const float lf = l + __shfl_xor(l, 32);
  const float inv = 1.f / lf;
  char* ep = lds + w * 8448;  // 32 rows x 264B (padded)
#pragma unroll
  for (int rf = 0; rf < 4; ++rf)
#pragma unroll
    for (int g = 0; g < 4; ++g) {
      const unsigned u0 = pk2bf(oacc[rf][4 * g + 0] * inv, oacc[rf][4 * g + 1] * inv);
      const unsigned u1 = pk2bf(oacc[rf][4 * g + 2] * inv, oacc[rf][4 * g + 3] * inv);
      *(uint2*)(ep + l31 * 264 + rf * 64 + g * 16 + hi * 8) = make_uint2(u0, u1);
    }
  __syncthreads();
  const int c = lane & 15, l4b = lane >> 4;
#pragma unroll
  for (int pass = 0; pass < 8; ++pass) {
    const int qq = pass * 4 + l4b;
    const uint2 a2 = *(const uint2*)(ep + qq * 264 + c * 16);
    const uint2 b2 = *(const uint2*)(ep + qq * 264 + c * 16 + 8);
    *(uint4*)(A2 + (size_t)(q0 + qq) * 15360 + h * 128 + c * 8) =
        make_uint4(a2.x, a2.y, b2.x, b2.y);
  }
#undef ATT_STAGE
}

// ---------------- launch ----------------
extern "C" void kernel_launch(void* const* d_in, const int* in_sizes, int n_in,
                              void* d_out, int out_size, void* d_ws, size_t ws_size,
                              hipStream_t stream) {
  (void)in_sizes; (void)n_in; (void)out_size; (void)ws_size;
  const float* img    = (const float*)d_in[0];
  const float* vec    = (const float*)d_in[1];
  const float* pe     = (const float*)d_in[2];
  const float* mod_w  = (const float*)d_in[3];
  const float* mod_b  = (const float*)d_in[4];
  const float* lin1_w = (const float*)d_in[5];
  const float* lin1_b = (const float*)d_in[6];
  const float* lin2_w = (const float*)d_in[7];
  const float* lin2_b = (const float*)d_in[8];
  const float* q_s    = (const float*)d_in[9];
  const float* k_s    = (const float*)d_in[10];
  float* out = (float*)d_out;

  char* ws = (char*)d_ws;
  size_t off = 0;
  auto alloc = [&](size_t b) { size_t p = off; off += (b + 255) & ~(size_t)255; return p; };
  float* part          = (float*)(ws + alloc((size_t)8 * 9216 * 4));
  float* mod           = (float*)(ws + alloc((size_t)9216 * 4));
  unsigned short* x    = (unsigned short*)(ws + alloc((size_t)2048 * 3072 * 2));
  unsigned short* wT   = (unsigned short*)(ws + alloc((size_t)21504 * 3072 * 2));  // w1t then w2t
  unsigned short* proj = (unsigned short*)(ws + alloc((size_t)2048 * 21504 * 2));
  unsigned short* qr   = (unsigned short*)(ws + alloc((size_t)24 * 2048 * 128 * 2));
  unsigned short* kr   = (unsigned short*)(ws + alloc((size_t)24 * 2048 * 128 * 2));
  unsigned short* vt   = (unsigned short*)(ws + alloc((size_t)24 * 128 * 2048 * 2));
  unsigned short* A2   = (unsigned short*)(ws + alloc((size_t)2048 * 15360 * 2));
  float* p2buf = (float*)proj;  // gemm2 split-K partials reuse dead proj buffer

  modvec_partial<<<dim3(36, 8), 256, 0, stream>>>(vec, mod_w, part);
  modvec_reduce<<<36, 256, 0, stream>>>(part, mod_b, mod);
  ln_mod_kernel<<<2048, 256, 0, stream>>>(img, mod, x);
  transpose_kernel<<<dim3(48, 336), 256, 0, stream>>>(lin1_w, wT, 3072, 21504);
  gemm256_kernel<0><<<672, 512, 0, stream>>>(x, wT, lin1_b, proj, 3072, 21504, 48, 84);
  qk_prep_kernel<<<2048, 256, 0, stream>>>(proj, pe, q_s, k_s, qr, kr, vt);
  gelu_kernel<<<12288, 256, 0, stream>>>(proj, A2);
  attn_kernel<<<dim3(16, 24), 256, 0, stream>>>(qr, kr, vt, A2);
  transpose_kernel<<<dim3(240, 48), 256, 0, stream>>>(lin2_w, wT, 15360, 3072);
  gemm256_kernel<2><<<192, 512, 0, stream>>>(A2, wT, nullptr, p2buf, 15360, 3072, 120, 12);
  reduce2_kernel<<<6144, 256, 0, stream>>>(p2buf, img, mod, lin2_b, out);
}